// Round 6
// baseline (1145.090 us; speedup 1.0000x reference)
//
#include <hip/hip_runtime.h>

#define TN 64
#define NB 2
#define CH 8
#define HH 128
#define WW 128
#define HW (HH*WW)        // 16384
#define CHW (CH*HW)       // 131072
#define NCHW (NB*CHW)     // 262144

// ---------------------------------------------------------------------------
// K1: psp1 alpha filter (tau=1). One thread per (n,c,h,w) element.
// ---------------------------------------------------------------------------
__global__ __launch_bounds__(256) void k_psp1(const float* __restrict__ x,
                                              float* __restrict__ psp1) {
    int e = blockIdx.x * blockDim.x + threadIdx.x;
    if (e >= NCHW) return;
    const float d1 = 0.36787944117144233f;  // exp(-1)
    const float c1 = 2.7182818284590452f;   // e * Ts/tau * Ts
    float P = 0.f, Q = 0.f;
    const float4* xe = reinterpret_cast<const float4*>(x + (size_t)e * TN);
    #pragma unroll
    for (int t4 = 0; t4 < TN / 4; ++t4) {
        float4 xv = xe[t4];
        float xs[4] = {xv.x, xv.y, xv.z, xv.w};
        #pragma unroll
        for (int j = 0; j < 4; ++j) {
            Q = d1 * (Q + P);
            P = d1 * P + xs[j];
            psp1[(size_t)(t4 * 4 + j) * NCHW + e] = c1 * Q;
        }
    }
}

// ---------------------------------------------------------------------------
// K2: conv1 5x5 pad=2. Identical structure to R5 EXCEPT: weights are copied
// to LDS once per block, so inner-loop weight reads are in-order DS ops
// (uniform-address broadcast) instead of out-of-order SMEM -> the compiler
// can use precise lgkmcnt(N) waits instead of full drains.
// ---------------------------------------------------------------------------
__global__ __launch_bounds__(256, 4) void k_conv1(const float* __restrict__ in,
                                                  const float* __restrict__ w1,
                                                  float* __restrict__ outp) {
    __shared__ __align__(16) float tile[2][2][12][136];
    __shared__ __align__(16) float wlds[CH * CH * 25];     // 1600 floats
    const int img = blockIdx.y;                 // t*NB + n, 0..127
    const int h0 = blockIdx.x * 8;              // 16 y-tiles
    const int tid = threadIdx.x;
    const int yi = tid >> 5;                    // 0..7
    const int x0 = (tid & 31) * 4;              // 0..124
    const float* base = in + (size_t)img * CHW;

    // copy weights to LDS (coalesced); visible after first __syncthreads
    for (int i = tid; i < CH * CH * 25; i += 256) wlds[i] = w1[i];

    // staging offsets: computed ONCE, reused for all 4 channel-pair phases
    int goff[7];
    #pragma unroll
    for (int k = 0; k < 7; ++k) {
        int idx = tid + (k << 8);
        int r = idx / 136;
        int c = idx - r * 136;
        int gh = h0 + r - 2, gw = c - 2;
        bool ok = (idx < 1632) && (gh >= 0) && (gh < HH) && (gw >= 0) && (gw < WW);
        goff[k] = ok ? (gh * WW + gw) : -1;
    }

    float va[7], vb[7];
    // prefetch channel pair 0 (branchless clamped loads)
    #pragma unroll
    for (int k = 0; k < 7; ++k) {
        int g = goff[k];
        int gc = g < 0 ? 0 : g;
        float t0 = base[gc], t1 = base[HW + gc];
        va[k] = g < 0 ? 0.f : t0;
        vb[k] = g < 0 ? 0.f : t1;
    }

    float acc[CH][4];
    #pragma unroll
    for (int co = 0; co < CH; ++co)
        #pragma unroll
        for (int xo = 0; xo < 4; ++xo) acc[co][xo] = 0.f;

    for (int cig = 0; cig < 4; ++cig) {
        float* dst = &tile[cig & 1][0][0][0];
        #pragma unroll
        for (int k = 0; k < 7; ++k) {
            int idx = tid + (k << 8);
            if (k < 6 || idx < 1632) {
                dst[idx]        = va[k];
                dst[1632 + idx] = vb[k];
            }
        }
        if (cig < 3) {                           // prefetch next pair -> regs
            const float* nb = base + (size_t)(cig + 1) * 2 * HW;
            #pragma unroll
            for (int k = 0; k < 7; ++k) {
                int g = goff[k];
                int gc = g < 0 ? 0 : g;
                float t0 = nb[gc], t1 = nb[HW + gc];
                va[k] = g < 0 ? 0.f : t0;
                vb[k] = g < 0 ? 0.f : t1;
            }
        }
        __syncthreads();                         // staged data (+weights) visible

        const float* bufp = &tile[cig & 1][0][0][0];
        #pragma unroll
        for (int c = 0; c < 2; ++c) {
            const int ci = cig * 2 + c;
            const float* chp = bufp + c * 1632;
            #pragma unroll
            for (int ky = 0; ky < 5; ++ky) {
                const float4* rp =
                    reinterpret_cast<const float4*>(chp + (yi + ky) * 136 + x0);
                float4 A = rp[0], B = rp[1];
                float f[8] = {A.x, A.y, A.z, A.w, B.x, B.y, B.z, B.w};
                #pragma unroll
                for (int co = 0; co < CH; ++co) {
                    const float* wp = wlds + (co * CH + ci) * 25 + ky * 5;
                    #pragma unroll
                    for (int kx = 0; kx < 5; ++kx) {
                        float wv = wp[kx];
                        #pragma unroll
                        for (int xo = 0; xo < 4; ++xo)
                            acc[co][xo] = fmaf(wv, f[kx + xo], acc[co][xo]);
                    }
                }
            }
        }
        // no trailing barrier: next phase writes the OTHER LDS buffer
    }

    float* ob = outp + (size_t)img * CHW + (h0 + yi) * WW + x0;
    #pragma unroll
    for (int co = 0; co < CH; ++co)
        *reinterpret_cast<float4*>(ob + co * HW) =
            make_float4(acc[co][0], acc[co][1], acc[co][2], acc[co][3]);
}

// ---------------------------------------------------------------------------
// K3: LIF1 (theta=30, tauRef=1) + psp2 alpha filter (tau=2), fused pointwise.
// ---------------------------------------------------------------------------
__global__ __launch_bounds__(256) void k_lif1_psp2(const float* __restrict__ u1,
                                                   float* __restrict__ psp2) {
    int e = blockIdx.x * blockDim.x + threadIdx.x;
    if (e >= NCHW) return;
    const float dr = 0.36787944117144233f;  // exp(-1)
    const float rg = 81.54845485377136f;    // 30*e
    const float th = 30.f;
    const float d2 = 0.60653065971263342f;  // exp(-0.5)
    const float c2 = 1.35914091422952262f;  // e/2
    float Pr = 0.f, Qr = 0.f, P2 = 0.f, Q2 = 0.f;
    #pragma unroll 8
    for (int t = 0; t < TN; ++t) {
        Qr = dr * (Qr + Pr);
        float u = u1[(size_t)t * NCHW + e];
        float s = (u - rg * Qr >= th) ? 1.0f : 0.0f;
        Pr = dr * Pr + s;
        Q2 = d2 * (Q2 + P2);
        P2 = d2 * P2 + s;
        psp2[(size_t)t * NCHW + e] = c2 * Q2;
    }
}

// ---------------------------------------------------------------------------
// K4: conv2 3x3 pad=1. Same structure as K2 (weights in LDS).
// ---------------------------------------------------------------------------
__global__ __launch_bounds__(256, 4) void k_conv2(const float* __restrict__ in,
                                                  const float* __restrict__ w2,
                                                  float* __restrict__ outp) {
    __shared__ __align__(16) float tile[2][2][10][136];
    __shared__ __align__(16) float wlds[CH * CH * 9];      // 576 floats
    const int img = blockIdx.y;
    const int h0 = blockIdx.x * 8;
    const int tid = threadIdx.x;
    const int yi = tid >> 5;
    const int x0 = (tid & 31) * 4;
    const float* base = in + (size_t)img * CHW;

    for (int i = tid; i < CH * CH * 9; i += 256) wlds[i] = w2[i];

    int goff[6];
    #pragma unroll
    for (int k = 0; k < 6; ++k) {
        int idx = tid + (k << 8);
        int r = idx / 136;
        int c = idx - r * 136;
        int gh = h0 + r - 1, gw = c - 1;
        bool ok = (idx < 1360) && (gh >= 0) && (gh < HH) && (gw >= 0) && (gw < WW);
        goff[k] = ok ? (gh * WW + gw) : -1;
    }

    float va[6], vb[6];
    #pragma unroll
    for (int k = 0; k < 6; ++k) {
        int g = goff[k];
        int gc = g < 0 ? 0 : g;
        float t0 = base[gc], t1 = base[HW + gc];
        va[k] = g < 0 ? 0.f : t0;
        vb[k] = g < 0 ? 0.f : t1;
    }

    float acc[CH][4];
    #pragma unroll
    for (int co = 0; co < CH; ++co)
        #pragma unroll
        for (int xo = 0; xo < 4; ++xo) acc[co][xo] = 0.f;

    for (int cig = 0; cig < 4; ++cig) {
        float* dst = &tile[cig & 1][0][0][0];
        #pragma unroll
        for (int k = 0; k < 6; ++k) {
            int idx = tid + (k << 8);
            if (k < 5 || idx < 1360) {
                dst[idx]        = va[k];
                dst[1360 + idx] = vb[k];
            }
        }
        if (cig < 3) {
            const float* nb = base + (size_t)(cig + 1) * 2 * HW;
            #pragma unroll
            for (int k = 0; k < 6; ++k) {
                int g = goff[k];
                int gc = g < 0 ? 0 : g;
                float t0 = nb[gc], t1 = nb[HW + gc];
                va[k] = g < 0 ? 0.f : t0;
                vb[k] = g < 0 ? 0.f : t1;
            }
        }
        __syncthreads();

        const float* bufp = &tile[cig & 1][0][0][0];
        #pragma unroll
        for (int c = 0; c < 2; ++c) {
            const int ci = cig * 2 + c;
            const float* chp = bufp + c * 1360;
            #pragma unroll
            for (int ky = 0; ky < 3; ++ky) {
                const float4* rp =
                    reinterpret_cast<const float4*>(chp + (yi + ky) * 136 + x0);
                float4 A = rp[0], B = rp[1];
                float f[8] = {A.x, A.y, A.z, A.w, B.x, B.y, B.z, B.w};
                #pragma unroll
                for (int co = 0; co < CH; ++co) {
                    const float* wp = wlds + (co * CH + ci) * 9 + ky * 3;
                    #pragma unroll
                    for (int kx = 0; kx < 3; ++kx) {
                        float wv = wp[kx];
                        #pragma unroll
                        for (int xo = 0; xo < 4; ++xo)
                            acc[co][xo] = fmaf(wv, f[kx + xo], acc[co][xo]);
                    }
                }
            }
        }
    }

    float* ob = outp + (size_t)img * CHW + (h0 + yi) * WW + x0;
    #pragma unroll
    for (int co = 0; co < CH; ++co)
        *reinterpret_cast<float4*>(ob + co * HW) =
            make_float4(acc[co][0], acc[co][1], acc[co][2], acc[co][3]);
}

// ---------------------------------------------------------------------------
// K5: LIF2 (theta=50, tauRef=2). Buffers 64 spikes in registers, writes
// output [N,C,H,W,T] (t-contiguous per thread) as float4.
// ---------------------------------------------------------------------------
__global__ __launch_bounds__(256) void k_lif2(const float* __restrict__ u2,
                                              float* __restrict__ outp) {
    int e = blockIdx.x * blockDim.x + threadIdx.x;
    if (e >= NCHW) return;
    const float dr = 0.60653065971263342f;  // exp(-0.5)
    const float rg = 67.95704571147613f;    // 25*e
    const float th = 50.f;
    float Pr = 0.f, Qr = 0.f;
    float sv[TN];
    #pragma unroll
    for (int t = 0; t < TN; ++t) {
        Qr = dr * (Qr + Pr);
        float u = u2[(size_t)t * NCHW + e];
        float s = (u - rg * Qr >= th) ? 1.0f : 0.0f;
        Pr = dr * Pr + s;
        sv[t] = s;
    }
    float4* o = reinterpret_cast<float4*>(outp + (size_t)e * TN);
    #pragma unroll
    for (int i = 0; i < TN / 4; ++i)
        o[i] = make_float4(sv[4 * i], sv[4 * i + 1], sv[4 * i + 2], sv[4 * i + 3]);
}

// ---------------------------------------------------------------------------
extern "C" void kernel_launch(void* const* d_in, const int* in_sizes, int n_in,
                              void* d_out, int out_size, void* d_ws, size_t ws_size,
                              hipStream_t stream) {
    const float* x  = (const float*)d_in[0];   // [2,8,128,128,64]
    const float* w1 = (const float*)d_in[1];   // [8,8,5,5]
    const float* w2 = (const float*)d_in[2];   // [8,8,3,3]
    float* out = (float*)d_out;                // [2,8,128,128,64]

    float* bufA = (float*)d_ws;                       // psp1, then psp2
    float* bufB = bufA + (size_t)TN * NCHW;           // u1,   then u2

    dim3 blk(256);
    dim3 grd_pt(NCHW / 256);          // 1024 blocks, pointwise kernels
    dim3 grd_cv(16, TN * NB);         // 16 row-tiles (8 rows) x 128 images

    k_psp1<<<grd_pt, blk, 0, stream>>>(x, bufA);
    k_conv1<<<grd_cv, blk, 0, stream>>>(bufA, w1, bufB);
    k_lif1_psp2<<<grd_pt, blk, 0, stream>>>(bufB, bufA);
    k_conv2<<<grd_cv, blk, 0, stream>>>(bufA, w2, bufB);
    k_lif2<<<grd_pt, blk, 0, stream>>>(bufB, out);
}

// Round 7
// 666.482 us; speedup vs baseline: 1.7181x; 1.7181x over previous
//
#include <hip/hip_runtime.h>

#define TN 64
#define NB 2
#define CH 8
#define HH 128
#define WW 128
#define HW (HH*WW)        // 16384
#define CHW (CH*HW)       // 131072
#define NCHW (NB*CHW)     // 262144

// ---------------------------------------------------------------------------
// K1: psp1 alpha filter (tau=1). One thread per (n,c,h,w) element.
// ---------------------------------------------------------------------------
__global__ __launch_bounds__(256) void k_psp1(const float* __restrict__ x,
                                              float* __restrict__ psp1) {
    int e = blockIdx.x * blockDim.x + threadIdx.x;
    if (e >= NCHW) return;
    const float d1 = 0.36787944117144233f;  // exp(-1)
    const float c1 = 2.7182818284590452f;   // e * Ts/tau * Ts
    float P = 0.f, Q = 0.f;
    const float4* xe = reinterpret_cast<const float4*>(x + (size_t)e * TN);
    #pragma unroll
    for (int t4 = 0; t4 < TN / 4; ++t4) {
        float4 xv = xe[t4];
        float xs[4] = {xv.x, xv.y, xv.z, xv.w};
        #pragma unroll
        for (int j = 0; j < 4; ++j) {
            Q = d1 * (Q + P);
            P = d1 * P + xs[j];
            psp1[(size_t)(t4 * 4 + j) * NCHW + e] = c1 * Q;
        }
    }
}

// ---------------------------------------------------------------------------
// K2: conv1 5x5 pad=2, 8->8 ch. LDS-FREE: one wave = one output row.
// 64 lanes x 2 px; per (ci,ky) one coalesced float2 load (L1/L2-hit),
// halo via __shfl from neighbor lanes, zero-pad at row ends via select.
// Weights via uniform global loads -> SGPR (s_load), free FMA operands.
// No barriers, no LDS. Accumulation order (ci,ky,kx) preserved -> bit-exact.
// ---------------------------------------------------------------------------
__global__ __launch_bounds__(256) void k_conv1(const float* __restrict__ in,
                                               const float* __restrict__ w1,
                                               float* __restrict__ outp) {
    const int tid  = threadIdx.x;
    const int lane = tid & 63;
    const int wid  = tid >> 6;                       // 0..3
    const int img  = blockIdx.x >> 5;                // 0..127
    const int y    = ((blockIdx.x & 31) << 2) + wid; // 0..127
    const int x0   = lane << 1;                      // 0..126
    const float* base = in + (size_t)img * CHW + x0;
    const bool lo = (lane == 0), hi = (lane == 63);

    float acc[CH][2];
    #pragma unroll
    for (int co = 0; co < CH; ++co) { acc[co][0] = 0.f; acc[co][1] = 0.f; }

    #pragma unroll
    for (int ci = 0; ci < CH; ++ci) {
        const float* rb = base + ci * HW + (y - 2) * WW;
        float w6[5][6];
        #pragma unroll
        for (int ky = 0; ky < 5; ++ky) {
            int yy = y + ky - 2;
            float2 t = make_float2(0.f, 0.f);
            if (yy >= 0 && yy < HH)
                t = *reinterpret_cast<const float2*>(rb + ky * WW);
            float lx = __shfl(t.x, lane - 1);
            float ly = __shfl(t.y, lane - 1);
            float rx = __shfl(t.x, lane + 1);
            float ry = __shfl(t.y, lane + 1);
            w6[ky][0] = lo ? 0.f : lx;
            w6[ky][1] = lo ? 0.f : ly;
            w6[ky][2] = t.x;
            w6[ky][3] = t.y;
            w6[ky][4] = hi ? 0.f : rx;
            w6[ky][5] = hi ? 0.f : ry;
        }
        #pragma unroll
        for (int ky = 0; ky < 5; ++ky) {
            #pragma unroll
            for (int co = 0; co < CH; ++co) {
                const float* wp = w1 + (co * CH + ci) * 25 + ky * 5;
                #pragma unroll
                for (int kx = 0; kx < 5; ++kx) {
                    float wv = wp[kx];
                    acc[co][0] = fmaf(wv, w6[ky][kx],     acc[co][0]);
                    acc[co][1] = fmaf(wv, w6[ky][kx + 1], acc[co][1]);
                }
            }
        }
    }

    float* ob = outp + (size_t)img * CHW + y * WW + x0;
    #pragma unroll
    for (int co = 0; co < CH; ++co)
        *reinterpret_cast<float2*>(ob + co * HW) = make_float2(acc[co][0], acc[co][1]);
}

// ---------------------------------------------------------------------------
// K3: LIF1 (theta=30, tauRef=1) + psp2 alpha filter (tau=2), fused pointwise.
// ---------------------------------------------------------------------------
__global__ __launch_bounds__(256) void k_lif1_psp2(const float* __restrict__ u1,
                                                   float* __restrict__ psp2) {
    int e = blockIdx.x * blockDim.x + threadIdx.x;
    if (e >= NCHW) return;
    const float dr = 0.36787944117144233f;  // exp(-1)
    const float rg = 81.54845485377136f;    // 30*e
    const float th = 30.f;
    const float d2 = 0.60653065971263342f;  // exp(-0.5)
    const float c2 = 1.35914091422952262f;  // e/2
    float Pr = 0.f, Qr = 0.f, P2 = 0.f, Q2 = 0.f;
    #pragma unroll 8
    for (int t = 0; t < TN; ++t) {
        Qr = dr * (Qr + Pr);
        float u = u1[(size_t)t * NCHW + e];
        float s = (u - rg * Qr >= th) ? 1.0f : 0.0f;
        Pr = dr * Pr + s;
        Q2 = d2 * (Q2 + P2);
        P2 = d2 * P2 + s;
        psp2[(size_t)t * NCHW + e] = c2 * Q2;
    }
}

// ---------------------------------------------------------------------------
// K4: conv2 3x3 pad=1, 8->8 ch. Same LDS-free structure as K2.
// Window = 4 floats: only 2 shuffles per (ci,ky).
// ---------------------------------------------------------------------------
__global__ __launch_bounds__(256) void k_conv2(const float* __restrict__ in,
                                               const float* __restrict__ w2,
                                               float* __restrict__ outp) {
    const int tid  = threadIdx.x;
    const int lane = tid & 63;
    const int wid  = tid >> 6;
    const int img  = blockIdx.x >> 5;
    const int y    = ((blockIdx.x & 31) << 2) + wid;
    const int x0   = lane << 1;
    const float* base = in + (size_t)img * CHW + x0;
    const bool lo = (lane == 0), hi = (lane == 63);

    float acc[CH][2];
    #pragma unroll
    for (int co = 0; co < CH; ++co) { acc[co][0] = 0.f; acc[co][1] = 0.f; }

    #pragma unroll
    for (int ci = 0; ci < CH; ++ci) {
        const float* rb = base + ci * HW + (y - 1) * WW;
        float w4[3][4];
        #pragma unroll
        for (int ky = 0; ky < 3; ++ky) {
            int yy = y + ky - 1;
            float2 t = make_float2(0.f, 0.f);
            if (yy >= 0 && yy < HH)
                t = *reinterpret_cast<const float2*>(rb + ky * WW);
            float ly = __shfl(t.y, lane - 1);
            float rx = __shfl(t.x, lane + 1);
            w4[ky][0] = lo ? 0.f : ly;
            w4[ky][1] = t.x;
            w4[ky][2] = t.y;
            w4[ky][3] = hi ? 0.f : rx;
        }
        #pragma unroll
        for (int ky = 0; ky < 3; ++ky) {
            #pragma unroll
            for (int co = 0; co < CH; ++co) {
                const float* wp = w2 + (co * CH + ci) * 9 + ky * 3;
                #pragma unroll
                for (int kx = 0; kx < 3; ++kx) {
                    float wv = wp[kx];
                    acc[co][0] = fmaf(wv, w4[ky][kx],     acc[co][0]);
                    acc[co][1] = fmaf(wv, w4[ky][kx + 1], acc[co][1]);
                }
            }
        }
    }

    float* ob = outp + (size_t)img * CHW + y * WW + x0;
    #pragma unroll
    for (int co = 0; co < CH; ++co)
        *reinterpret_cast<float2*>(ob + co * HW) = make_float2(acc[co][0], acc[co][1]);
}

// ---------------------------------------------------------------------------
// K5: LIF2 (theta=50, tauRef=2). Buffers 64 spikes in registers, writes
// output [N,C,H,W,T] (t-contiguous per thread) as float4.
// ---------------------------------------------------------------------------
__global__ __launch_bounds__(256) void k_lif2(const float* __restrict__ u2,
                                              float* __restrict__ outp) {
    int e = blockIdx.x * blockDim.x + threadIdx.x;
    if (e >= NCHW) return;
    const float dr = 0.60653065971263342f;  // exp(-0.5)
    const float rg = 67.95704571147613f;    // 25*e
    const float th = 50.f;
    float Pr = 0.f, Qr = 0.f;
    float sv[TN];
    #pragma unroll
    for (int t = 0; t < TN; ++t) {
        Qr = dr * (Qr + Pr);
        float u = u2[(size_t)t * NCHW + e];
        float s = (u - rg * Qr >= th) ? 1.0f : 0.0f;
        Pr = dr * Pr + s;
        sv[t] = s;
    }
    float4* o = reinterpret_cast<float4*>(outp + (size_t)e * TN);
    #pragma unroll
    for (int i = 0; i < TN / 4; ++i)
        o[i] = make_float4(sv[4 * i], sv[4 * i + 1], sv[4 * i + 2], sv[4 * i + 3]);
}

// ---------------------------------------------------------------------------
extern "C" void kernel_launch(void* const* d_in, const int* in_sizes, int n_in,
                              void* d_out, int out_size, void* d_ws, size_t ws_size,
                              hipStream_t stream) {
    const float* x  = (const float*)d_in[0];   // [2,8,128,128,64]
    const float* w1 = (const float*)d_in[1];   // [8,8,5,5]
    const float* w2 = (const float*)d_in[2];   // [8,8,3,3]
    float* out = (float*)d_out;                // [2,8,128,128,64]

    float* bufA = (float*)d_ws;                       // psp1, then psp2
    float* bufB = bufA + (size_t)TN * NCHW;           // u1,   then u2

    dim3 blk(256);
    dim3 grd_pt(NCHW / 256);          // 1024 blocks, pointwise kernels
    dim3 grd_cv(4096);                // 128 img x 32 row-quads

    k_psp1<<<grd_pt, blk, 0, stream>>>(x, bufA);
    k_conv1<<<grd_cv, blk, 0, stream>>>(bufA, w1, bufB);
    k_lif1_psp2<<<grd_pt, blk, 0, stream>>>(bufB, bufA);
    k_conv2<<<grd_cv, blk, 0, stream>>>(bufA, w2, bufB);
    k_lif2<<<grd_pt, blk, 0, stream>>>(bufB, out);
}

// Round 8
// 383.646 us; speedup vs baseline: 2.9848x; 1.7372x over previous
//
#include <hip/hip_runtime.h>

#define TN 64
#define NB 2
#define CH 8
#define HH 128
#define WW 128
#define HW (HH*WW)        // 16384
#define CHW (CH*HW)       // 131072
#define NCHW (NB*CHW)     // 262144

// ---------------------------------------------------------------------------
// K1: psp1 alpha filter (tau=1). One thread per (n,c,h,w) element.
// ---------------------------------------------------------------------------
__global__ __launch_bounds__(256) void k_psp1(const float* __restrict__ x,
                                              float* __restrict__ psp1) {
    int e = blockIdx.x * blockDim.x + threadIdx.x;
    if (e >= NCHW) return;
    const float d1 = 0.36787944117144233f;  // exp(-1)
    const float c1 = 2.7182818284590452f;   // e * Ts/tau * Ts
    float P = 0.f, Q = 0.f;
    const float4* xe = reinterpret_cast<const float4*>(x + (size_t)e * TN);
    #pragma unroll
    for (int t4 = 0; t4 < TN / 4; ++t4) {
        float4 xv = xe[t4];
        float xs[4] = {xv.x, xv.y, xv.z, xv.w};
        #pragma unroll
        for (int j = 0; j < 4; ++j) {
            Q = d1 * (Q + P);
            P = d1 * P + xs[j];
            psp1[(size_t)(t4 * 4 + j) * NCHW + e] = c1 * Q;
        }
    }
}

// ---------------------------------------------------------------------------
// K2: conv1 5x5 pad=2. Block = 256 thr = 16 rows x 16 lanes x 8 px.
// Double-buffered LDS [2buf][2ch][20][136] = 43.5 KB, 1 barrier/phase.
// Per (ci,ky): 3 ds_read_b128 -> 320 FMAs (8 FMA per weight fetch).
// Weights via SMEM (uniform s_load, free FMA operands). acc[8][8] = 64 VGPR.
// ---------------------------------------------------------------------------
__global__ __launch_bounds__(256, 3) void k_conv1(const float* __restrict__ in,
                                                  const float* __restrict__ w1,
                                                  float* __restrict__ outp) {
    __shared__ __align__(16) float tile[2][2][20][136];
    const int img = blockIdx.y;                 // t*NB + n, 0..127
    const int h0 = blockIdx.x * 16;             // 8 y-tiles
    const int tid = threadIdx.x;
    const int yi = tid >> 4;                    // 0..15
    const int x0 = (tid & 15) * 8;              // 0..120
    const float* base = in + (size_t)img * CHW;

    // staging offsets: computed ONCE, reused for all 4 channel-pair phases
    int goff[11];                               // 20*136 = 2720 slots
    #pragma unroll
    for (int k = 0; k < 11; ++k) {
        int idx = tid + (k << 8);
        int r = idx / 136;
        int c = idx - r * 136;
        int gh = h0 + r - 2, gw = c - 2;
        bool ok = (idx < 2720) && (gh >= 0) && (gh < HH) && (gw >= 0) && (gw < WW);
        goff[k] = ok ? (gh * WW + gw) : -1;
    }

    float va[11], vb[11];
    #pragma unroll
    for (int k = 0; k < 11; ++k) {
        int g = goff[k];
        int gc = g < 0 ? 0 : g;
        float t0 = base[gc], t1 = base[HW + gc];
        va[k] = g < 0 ? 0.f : t0;
        vb[k] = g < 0 ? 0.f : t1;
    }

    float acc[CH][8];
    #pragma unroll
    for (int co = 0; co < CH; ++co)
        #pragma unroll
        for (int xo = 0; xo < 8; ++xo) acc[co][xo] = 0.f;

    for (int cig = 0; cig < 4; ++cig) {
        float* dst = &tile[cig & 1][0][0][0];
        #pragma unroll
        for (int k = 0; k < 11; ++k) {
            int idx = tid + (k << 8);
            if (k < 10 || idx < 2720) {
                dst[idx]        = va[k];
                dst[2720 + idx] = vb[k];
            }
        }
        if (cig < 3) {                           // prefetch next pair -> regs
            const float* nb = base + (size_t)(cig + 1) * 2 * HW;
            #pragma unroll
            for (int k = 0; k < 11; ++k) {
                int g = goff[k];
                int gc = g < 0 ? 0 : g;
                float t0 = nb[gc], t1 = nb[HW + gc];
                va[k] = g < 0 ? 0.f : t0;
                vb[k] = g < 0 ? 0.f : t1;
            }
        }
        __syncthreads();                         // staged data visible

        const float* bufp = &tile[cig & 1][0][0][0];
        #pragma unroll
        for (int c = 0; c < 2; ++c) {
            const int ci = cig * 2 + c;
            const float* chp = bufp + c * 2720;
            #pragma unroll
            for (int ky = 0; ky < 5; ++ky) {
                const float4* rp =
                    reinterpret_cast<const float4*>(chp + (yi + ky) * 136 + x0);
                float4 A = rp[0], B = rp[1], C = rp[2];
                float f[12] = {A.x, A.y, A.z, A.w, B.x, B.y, B.z, B.w,
                               C.x, C.y, C.z, C.w};
                #pragma unroll
                for (int co = 0; co < CH; ++co) {
                    const float* wp = w1 + (co * CH + ci) * 25 + ky * 5;
                    #pragma unroll
                    for (int kx = 0; kx < 5; ++kx) {
                        float wv = wp[kx];
                        #pragma unroll
                        for (int xo = 0; xo < 8; ++xo)
                            acc[co][xo] = fmaf(wv, f[kx + xo], acc[co][xo]);
                    }
                }
            }
        }
        // no trailing barrier: next phase writes the OTHER LDS buffer
    }

    float* ob = outp + (size_t)img * CHW + (h0 + yi) * WW + x0;
    #pragma unroll
    for (int co = 0; co < CH; ++co) {
        *reinterpret_cast<float4*>(ob + co * HW) =
            make_float4(acc[co][0], acc[co][1], acc[co][2], acc[co][3]);
        *reinterpret_cast<float4*>(ob + co * HW + 4) =
            make_float4(acc[co][4], acc[co][5], acc[co][6], acc[co][7]);
    }
}

// ---------------------------------------------------------------------------
// K3: LIF1 (theta=30, tauRef=1) + psp2 alpha filter (tau=2), fused pointwise.
// ---------------------------------------------------------------------------
__global__ __launch_bounds__(256) void k_lif1_psp2(const float* __restrict__ u1,
                                                   float* __restrict__ psp2) {
    int e = blockIdx.x * blockDim.x + threadIdx.x;
    if (e >= NCHW) return;
    const float dr = 0.36787944117144233f;  // exp(-1)
    const float rg = 81.54845485377136f;    // 30*e
    const float th = 30.f;
    const float d2 = 0.60653065971263342f;  // exp(-0.5)
    const float c2 = 1.35914091422952262f;  // e/2
    float Pr = 0.f, Qr = 0.f, P2 = 0.f, Q2 = 0.f;
    #pragma unroll 8
    for (int t = 0; t < TN; ++t) {
        Qr = dr * (Qr + Pr);
        float u = u1[(size_t)t * NCHW + e];
        float s = (u - rg * Qr >= th) ? 1.0f : 0.0f;
        Pr = dr * Pr + s;
        Q2 = d2 * (Q2 + P2);
        P2 = d2 * P2 + s;
        psp2[(size_t)t * NCHW + e] = c2 * Q2;
    }
}

// ---------------------------------------------------------------------------
// K4: conv2 3x3 pad=1. Same structure as K2.
// LDS [2][2][18][136] = 39.2 KB; per (ci,ky): 3 ds_read_b128 -> 192 FMA.
// ---------------------------------------------------------------------------
__global__ __launch_bounds__(256, 3) void k_conv2(const float* __restrict__ in,
                                                  const float* __restrict__ w2,
                                                  float* __restrict__ outp) {
    __shared__ __align__(16) float tile[2][2][18][136];
    const int img = blockIdx.y;
    const int h0 = blockIdx.x * 16;
    const int tid = threadIdx.x;
    const int yi = tid >> 4;
    const int x0 = (tid & 15) * 8;
    const float* base = in + (size_t)img * CHW;

    int goff[10];                               // 18*136 = 2448 slots
    #pragma unroll
    for (int k = 0; k < 10; ++k) {
        int idx = tid + (k << 8);
        int r = idx / 136;
        int c = idx - r * 136;
        int gh = h0 + r - 1, gw = c - 1;
        bool ok = (idx < 2448) && (gh >= 0) && (gh < HH) && (gw >= 0) && (gw < WW);
        goff[k] = ok ? (gh * WW + gw) : -1;
    }

    float va[10], vb[10];
    #pragma unroll
    for (int k = 0; k < 10; ++k) {
        int g = goff[k];
        int gc = g < 0 ? 0 : g;
        float t0 = base[gc], t1 = base[HW + gc];
        va[k] = g < 0 ? 0.f : t0;
        vb[k] = g < 0 ? 0.f : t1;
    }

    float acc[CH][8];
    #pragma unroll
    for (int co = 0; co < CH; ++co)
        #pragma unroll
        for (int xo = 0; xo < 8; ++xo) acc[co][xo] = 0.f;

    for (int cig = 0; cig < 4; ++cig) {
        float* dst = &tile[cig & 1][0][0][0];
        #pragma unroll
        for (int k = 0; k < 10; ++k) {
            int idx = tid + (k << 8);
            if (k < 9 || idx < 2448) {
                dst[idx]        = va[k];
                dst[2448 + idx] = vb[k];
            }
        }
        if (cig < 3) {
            const float* nb = base + (size_t)(cig + 1) * 2 * HW;
            #pragma unroll
            for (int k = 0; k < 10; ++k) {
                int g = goff[k];
                int gc = g < 0 ? 0 : g;
                float t0 = nb[gc], t1 = nb[HW + gc];
                va[k] = g < 0 ? 0.f : t0;
                vb[k] = g < 0 ? 0.f : t1;
            }
        }
        __syncthreads();

        const float* bufp = &tile[cig & 1][0][0][0];
        #pragma unroll
        for (int c = 0; c < 2; ++c) {
            const int ci = cig * 2 + c;
            const float* chp = bufp + c * 2448;
            #pragma unroll
            for (int ky = 0; ky < 3; ++ky) {
                const float4* rp =
                    reinterpret_cast<const float4*>(chp + (yi + ky) * 136 + x0);
                float4 A = rp[0], B = rp[1], C = rp[2];
                float f[12] = {A.x, A.y, A.z, A.w, B.x, B.y, B.z, B.w,
                               C.x, C.y, C.z, C.w};
                #pragma unroll
                for (int co = 0; co < CH; ++co) {
                    const float* wp = w2 + (co * CH + ci) * 9 + ky * 3;
                    #pragma unroll
                    for (int kx = 0; kx < 3; ++kx) {
                        float wv = wp[kx];
                        #pragma unroll
                        for (int xo = 0; xo < 8; ++xo)
                            acc[co][xo] = fmaf(wv, f[kx + xo], acc[co][xo]);
                    }
                }
            }
        }
    }

    float* ob = outp + (size_t)img * CHW + (h0 + yi) * WW + x0;
    #pragma unroll
    for (int co = 0; co < CH; ++co) {
        *reinterpret_cast<float4*>(ob + co * HW) =
            make_float4(acc[co][0], acc[co][1], acc[co][2], acc[co][3]);
        *reinterpret_cast<float4*>(ob + co * HW + 4) =
            make_float4(acc[co][4], acc[co][5], acc[co][6], acc[co][7]);
    }
}

// ---------------------------------------------------------------------------
// K5: LIF2 (theta=50, tauRef=2). Buffers 64 spikes in registers, writes
// output [N,C,H,W,T] (t-contiguous per thread) as float4.
// ---------------------------------------------------------------------------
__global__ __launch_bounds__(256) void k_lif2(const float* __restrict__ u2,
                                              float* __restrict__ outp) {
    int e = blockIdx.x * blockDim.x + threadIdx.x;
    if (e >= NCHW) return;
    const float dr = 0.60653065971263342f;  // exp(-0.5)
    const float rg = 67.95704571147613f;    // 25*e
    const float th = 50.f;
    float Pr = 0.f, Qr = 0.f;
    float sv[TN];
    #pragma unroll
    for (int t = 0; t < TN; ++t) {
        Qr = dr * (Qr + Pr);
        float u = u2[(size_t)t * NCHW + e];
        float s = (u - rg * Qr >= th) ? 1.0f : 0.0f;
        Pr = dr * Pr + s;
        sv[t] = s;
    }
    float4* o = reinterpret_cast<float4*>(outp + (size_t)e * TN);
    #pragma unroll
    for (int i = 0; i < TN / 4; ++i)
        o[i] = make_float4(sv[4 * i], sv[4 * i + 1], sv[4 * i + 2], sv[4 * i + 3]);
}

// ---------------------------------------------------------------------------
extern "C" void kernel_launch(void* const* d_in, const int* in_sizes, int n_in,
                              void* d_out, int out_size, void* d_ws, size_t ws_size,
                              hipStream_t stream) {
    const float* x  = (const float*)d_in[0];   // [2,8,128,128,64]
    const float* w1 = (const float*)d_in[1];   // [8,8,5,5]
    const float* w2 = (const float*)d_in[2];   // [8,8,3,3]
    float* out = (float*)d_out;                // [2,8,128,128,64]

    float* bufA = (float*)d_ws;                       // psp1, then psp2
    float* bufB = bufA + (size_t)TN * NCHW;           // u1,   then u2

    dim3 blk(256);
    dim3 grd_pt(NCHW / 256);          // 1024 blocks, pointwise kernels
    dim3 grd_cv(8, TN * NB);          // 8 row-tiles (16 rows) x 128 images

    k_psp1<<<grd_pt, blk, 0, stream>>>(x, bufA);
    k_conv1<<<grd_cv, blk, 0, stream>>>(bufA, w1, bufB);
    k_lif1_psp2<<<grd_pt, blk, 0, stream>>>(bufB, bufA);
    k_conv2<<<grd_cv, blk, 0, stream>>>(bufA, w2, bufB);
    k_lif2<<<grd_pt, blk, 0, stream>>>(bufB, out);
}

// Round 9
// 252.750 us; speedup vs baseline: 4.5305x; 1.5179x over previous
//
#include <hip/hip_runtime.h>

#define TN 64
#define NB 2
#define CH 8
#define HH 128
#define WW 128
#define HW (HH*WW)        // 16384
#define CHW (CH*HW)       // 131072
#define NCHW (NB*CHW)     // 262144

// ---------------------------------------------------------------------------
// K1: psp1 alpha filter (tau=1). One thread per (n,c,h,w) element.
// ---------------------------------------------------------------------------
__global__ __launch_bounds__(256) void k_psp1(const float* __restrict__ x,
                                              float* __restrict__ psp1) {
    int e = blockIdx.x * blockDim.x + threadIdx.x;
    if (e >= NCHW) return;
    const float d1 = 0.36787944117144233f;  // exp(-1)
    const float c1 = 2.7182818284590452f;   // e * Ts/tau * Ts
    float P = 0.f, Q = 0.f;
    const float4* xe = reinterpret_cast<const float4*>(x + (size_t)e * TN);
    #pragma unroll
    for (int t4 = 0; t4 < TN / 4; ++t4) {
        float4 xv = xe[t4];
        float xs[4] = {xv.x, xv.y, xv.z, xv.w};
        #pragma unroll
        for (int j = 0; j < 4; ++j) {
            Q = d1 * (Q + P);
            P = d1 * P + xs[j];
            psp1[(size_t)(t4 * 4 + j) * NCHW + e] = c1 * Q;
        }
    }
}

// ---------------------------------------------------------------------------
// K2: conv1 5x5 pad=2. Block = 256 thr = 8 rows x 32 lanes x 4 px.
// SINGLE-channel double-buffered phases: LDS [2buf][12][136] = 13.1 KB,
// 8 phases, 1 barrier each. va[7] prefetch regs; goff[] hoisted.
// Weights via SMEM (uniform s_load). acc[8][4] = 32 VGPR; total ~70 < 85 cap.
// ---------------------------------------------------------------------------
__global__ __launch_bounds__(256, 6) void k_conv1(const float* __restrict__ in,
                                                  const float* __restrict__ w1,
                                                  float* __restrict__ outp) {
    __shared__ __align__(16) float tile[2][12][136];
    const int img = blockIdx.y;                 // t*NB + n, 0..127
    const int h0 = blockIdx.x * 8;              // 16 y-tiles
    const int tid = threadIdx.x;
    const int yi = tid >> 5;                    // 0..7
    const int x0 = (tid & 31) * 4;              // 0..124
    const float* base = in + (size_t)img * CHW;

    // staging offsets: computed ONCE, reused for all 8 channel phases
    int goff[7];                                // 12*136 = 1632 slots
    #pragma unroll
    for (int k = 0; k < 7; ++k) {
        int idx = tid + (k << 8);
        int r = idx / 136;
        int c = idx - r * 136;
        int gh = h0 + r - 2, gw = c - 2;
        bool ok = (idx < 1632) && (gh >= 0) && (gh < HH) && (gw >= 0) && (gw < WW);
        goff[k] = ok ? (gh * WW + gw) : -1;
    }

    float va[7];
    #pragma unroll
    for (int k = 0; k < 7; ++k) {               // prefetch channel 0
        int g = goff[k];
        int gc = g < 0 ? 0 : g;
        float t0 = base[gc];
        va[k] = g < 0 ? 0.f : t0;
    }

    float acc[CH][4];
    #pragma unroll
    for (int co = 0; co < CH; ++co)
        #pragma unroll
        for (int xo = 0; xo < 4; ++xo) acc[co][xo] = 0.f;

    for (int ci = 0; ci < CH; ++ci) {
        float* dst = &tile[ci & 1][0][0];
        #pragma unroll
        for (int k = 0; k < 7; ++k) {
            int idx = tid + (k << 8);
            if (k < 6 || idx < 1632) dst[idx] = va[k];
        }
        if (ci < 7) {                            // prefetch next channel
            const float* nb = base + (size_t)(ci + 1) * HW;
            #pragma unroll
            for (int k = 0; k < 7; ++k) {
                int g = goff[k];
                int gc = g < 0 ? 0 : g;
                float t0 = nb[gc];
                va[k] = g < 0 ? 0.f : t0;
            }
        }
        __syncthreads();                         // staged data visible

        const float* chp = &tile[ci & 1][0][0];
        #pragma unroll
        for (int ky = 0; ky < 5; ++ky) {
            const float4* rp =
                reinterpret_cast<const float4*>(chp + (yi + ky) * 136 + x0);
            float4 A = rp[0], B = rp[1];
            float f[8] = {A.x, A.y, A.z, A.w, B.x, B.y, B.z, B.w};
            #pragma unroll
            for (int co = 0; co < CH; ++co) {
                const float* wp = w1 + (co * CH + ci) * 25 + ky * 5;
                #pragma unroll
                for (int kx = 0; kx < 5; ++kx) {
                    float wv = wp[kx];
                    #pragma unroll
                    for (int xo = 0; xo < 4; ++xo)
                        acc[co][xo] = fmaf(wv, f[kx + xo], acc[co][xo]);
                }
            }
        }
        // no trailing barrier: next phase writes the OTHER LDS buffer
    }

    float* ob = outp + (size_t)img * CHW + (h0 + yi) * WW + x0;
    #pragma unroll
    for (int co = 0; co < CH; ++co)
        *reinterpret_cast<float4*>(ob + co * HW) =
            make_float4(acc[co][0], acc[co][1], acc[co][2], acc[co][3]);
}

// ---------------------------------------------------------------------------
// K3: LIF1 (theta=30, tauRef=1) + psp2 alpha filter (tau=2), fused pointwise.
// ---------------------------------------------------------------------------
__global__ __launch_bounds__(256) void k_lif1_psp2(const float* __restrict__ u1,
                                                   float* __restrict__ psp2) {
    int e = blockIdx.x * blockDim.x + threadIdx.x;
    if (e >= NCHW) return;
    const float dr = 0.36787944117144233f;  // exp(-1)
    const float rg = 81.54845485377136f;    // 30*e
    const float th = 30.f;
    const float d2 = 0.60653065971263342f;  // exp(-0.5)
    const float c2 = 1.35914091422952262f;  // e/2
    float Pr = 0.f, Qr = 0.f, P2 = 0.f, Q2 = 0.f;
    #pragma unroll 8
    for (int t = 0; t < TN; ++t) {
        Qr = dr * (Qr + Pr);
        float u = u1[(size_t)t * NCHW + e];
        float s = (u - rg * Qr >= th) ? 1.0f : 0.0f;
        Pr = dr * Pr + s;
        Q2 = d2 * (Q2 + P2);
        P2 = d2 * P2 + s;
        psp2[(size_t)t * NCHW + e] = c2 * Q2;
    }
}

// ---------------------------------------------------------------------------
// K4: conv2 3x3 pad=1. Same single-channel dbuf structure as K2.
// LDS [2][10][136] = 10.9 KB; per (ci,ky): 2 ds_read_b128 -> 96 FMA.
// ---------------------------------------------------------------------------
__global__ __launch_bounds__(256, 6) void k_conv2(const float* __restrict__ in,
                                                  const float* __restrict__ w2,
                                                  float* __restrict__ outp) {
    __shared__ __align__(16) float tile[2][10][136];
    const int img = blockIdx.y;
    const int h0 = blockIdx.x * 8;
    const int tid = threadIdx.x;
    const int yi = tid >> 5;
    const int x0 = (tid & 31) * 4;
    const float* base = in + (size_t)img * CHW;

    int goff[6];                                // 10*136 = 1360 slots
    #pragma unroll
    for (int k = 0; k < 6; ++k) {
        int idx = tid + (k << 8);
        int r = idx / 136;
        int c = idx - r * 136;
        int gh = h0 + r - 1, gw = c - 1;
        bool ok = (idx < 1360) && (gh >= 0) && (gh < HH) && (gw >= 0) && (gw < WW);
        goff[k] = ok ? (gh * WW + gw) : -1;
    }

    float va[6];
    #pragma unroll
    for (int k = 0; k < 6; ++k) {
        int g = goff[k];
        int gc = g < 0 ? 0 : g;
        float t0 = base[gc];
        va[k] = g < 0 ? 0.f : t0;
    }

    float acc[CH][4];
    #pragma unroll
    for (int co = 0; co < CH; ++co)
        #pragma unroll
        for (int xo = 0; xo < 4; ++xo) acc[co][xo] = 0.f;

    for (int ci = 0; ci < CH; ++ci) {
        float* dst = &tile[ci & 1][0][0];
        #pragma unroll
        for (int k = 0; k < 6; ++k) {
            int idx = tid + (k << 8);
            if (k < 5 || idx < 1360) dst[idx] = va[k];
        }
        if (ci < 7) {
            const float* nb = base + (size_t)(ci + 1) * HW;
            #pragma unroll
            for (int k = 0; k < 6; ++k) {
                int g = goff[k];
                int gc = g < 0 ? 0 : g;
                float t0 = nb[gc];
                va[k] = g < 0 ? 0.f : t0;
            }
        }
        __syncthreads();

        const float* chp = &tile[ci & 1][0][0];
        #pragma unroll
        for (int ky = 0; ky < 3; ++ky) {
            const float4* rp =
                reinterpret_cast<const float4*>(chp + (yi + ky) * 136 + x0);
            float4 A = rp[0], B = rp[1];
            float f[8] = {A.x, A.y, A.z, A.w, B.x, B.y, B.z, B.w};
            #pragma unroll
            for (int co = 0; co < CH; ++co) {
                const float* wp = w2 + (co * CH + ci) * 9 + ky * 3;
                #pragma unroll
                for (int kx = 0; kx < 3; ++kx) {
                    float wv = wp[kx];
                    #pragma unroll
                    for (int xo = 0; xo < 4; ++xo)
                        acc[co][xo] = fmaf(wv, f[kx + xo], acc[co][xo]);
                }
            }
        }
    }

    float* ob = outp + (size_t)img * CHW + (h0 + yi) * WW + x0;
    #pragma unroll
    for (int co = 0; co < CH; ++co)
        *reinterpret_cast<float4*>(ob + co * HW) =
            make_float4(acc[co][0], acc[co][1], acc[co][2], acc[co][3]);
}

// ---------------------------------------------------------------------------
// K5: LIF2 (theta=50, tauRef=2). Buffers 64 spikes in registers, writes
// output [N,C,H,W,T] (t-contiguous per thread) as float4.
// ---------------------------------------------------------------------------
__global__ __launch_bounds__(256) void k_lif2(const float* __restrict__ u2,
                                              float* __restrict__ outp) {
    int e = blockIdx.x * blockDim.x + threadIdx.x;
    if (e >= NCHW) return;
    const float dr = 0.60653065971263342f;  // exp(-0.5)
    const float rg = 67.95704571147613f;    // 25*e
    const float th = 50.f;
    float Pr = 0.f, Qr = 0.f;
    float sv[TN];
    #pragma unroll
    for (int t = 0; t < TN; ++t) {
        Qr = dr * (Qr + Pr);
        float u = u2[(size_t)t * NCHW + e];
        float s = (u - rg * Qr >= th) ? 1.0f : 0.0f;
        Pr = dr * Pr + s;
        sv[t] = s;
    }
    float4* o = reinterpret_cast<float4*>(outp + (size_t)e * TN);
    #pragma unroll
    for (int i = 0; i < TN / 4; ++i)
        o[i] = make_float4(sv[4 * i], sv[4 * i + 1], sv[4 * i + 2], sv[4 * i + 3]);
}

// ---------------------------------------------------------------------------
extern "C" void kernel_launch(void* const* d_in, const int* in_sizes, int n_in,
                              void* d_out, int out_size, void* d_ws, size_t ws_size,
                              hipStream_t stream) {
    const float* x  = (const float*)d_in[0];   // [2,8,128,128,64]
    const float* w1 = (const float*)d_in[1];   // [8,8,5,5]
    const float* w2 = (const float*)d_in[2];   // [8,8,3,3]
    float* out = (float*)d_out;                // [2,8,128,128,64]

    float* bufA = (float*)d_ws;                       // psp1, then psp2
    float* bufB = bufA + (size_t)TN * NCHW;           // u1,   then u2

    dim3 blk(256);
    dim3 grd_pt(NCHW / 256);          // 1024 blocks, pointwise kernels
    dim3 grd_cv(16, TN * NB);         // 16 row-tiles (8 rows) x 128 images

    k_psp1<<<grd_pt, blk, 0, stream>>>(x, bufA);
    k_conv1<<<grd_cv, blk, 0, stream>>>(bufA, w1, bufB);
    k_lif1_psp2<<<grd_pt, blk, 0, stream>>>(bufB, bufA);
    k_conv2<<<grd_cv, blk, 0, stream>>>(bufA, w2, bufB);
    k_lif2<<<grd_pt, blk, 0, stream>>>(bufB, out);
}